// Round 1
// baseline (98.998 us; speedup 1.0000x reference)
//
#include <hip/hip_runtime.h>
#include <stdint.h>

#define NITEMS 10000
#define EDIM 32

constexpr int NB1 = 128;   // histogram blocks
constexpr int TB1 = 512;
constexpr int NB2 = 40;    // scoring blocks
constexpr int TB2 = 256;
constexpr int IPB = (NITEMS + NB2 - 1) / NB2;  // 250 items per scoring block

// ws layout:
// [0, 32768)            double partials[NB1][32]
// [32768, 32772)        unsigned int counter (zeroed each launch)
// [33024, 33024+3200)   u64 candidates[NB2 * K]

__global__ __launch_bounds__(TB1) void k1_hist_embsum(
    const int* __restrict__ hist, int H,
    const float* __restrict__ emb,
    double* __restrict__ partials)
{
    __shared__ int cnt[NITEMS];
    __shared__ double sred[TB1 / 32][32];

    for (int i = threadIdx.x; i < NITEMS; i += TB1) cnt[i] = 0;
    __syncthreads();

    // Phase 1: LDS histogram over this block's slice of history (vectorized int4)
    int tid = blockIdx.x * TB1 + threadIdx.x;
    int nth = gridDim.x * TB1;
    const int4* h4 = (const int4*)hist;
    int H4 = H >> 2;
    for (int i = tid; i < H4; i += nth) {
        int4 v = h4[i];
        atomicAdd(&cnt[v.x], 1);
        atomicAdd(&cnt[v.y], 1);
        atomicAdd(&cnt[v.z], 1);
        atomicAdd(&cnt[v.w], 1);
    }
    for (int i = (H4 << 2) + tid; i < H; i += nth) atomicAdd(&cnt[hist[i]], 1);
    __syncthreads();

    // Phase 2: partial[d] = sum_i cnt[i] * emb[i][d], accumulated in double.
    // Lane mapping: d = tid&31 -> 32 consecutive lanes read one emb row (coalesced 128B);
    // cnt[i] is a broadcast read within the group.
    int d = threadIdx.x & 31;
    int g = threadIdx.x >> 5;
    constexpr int NG = TB1 / 32;  // 16 groups
    double acc = 0.0;
    for (int i = g; i < NITEMS; i += NG) {
        acc += (double)cnt[i] * (double)emb[i * EDIM + d];
    }
    sred[g][d] = acc;
    __syncthreads();
    if (threadIdx.x < 32) {
        double s = 0.0;
        #pragma unroll
        for (int g2 = 0; g2 < NG; ++g2) s += sred[g2][threadIdx.x];
        partials[blockIdx.x * 32 + threadIdx.x] = s;  // plain store, no atomics
    }
}

__device__ __forceinline__ unsigned long long umax64(unsigned long long a, unsigned long long b) {
    return a > b ? a : b;
}

__global__ __launch_bounds__(TB2) void k2_score_topk(
    const double* __restrict__ partials,
    const float* __restrict__ emb,
    double invH,
    unsigned long long* __restrict__ cand,
    unsigned int* __restrict__ counter,
    int* __restrict__ out, int K)
{
    __shared__ float um[EDIM];
    __shared__ unsigned long long red[TB2];
    __shared__ int lastFlag;

    int t = threadIdx.x;

    // Finalize user mean embedding (redundantly per block; 4KB of L2 reads)
    if (t < EDIM) {
        double s = 0.0;
        #pragma unroll 8
        for (int b = 0; b < NB1; ++b) s += partials[b * EDIM + t];
        um[t] = (float)(s * invH);
    }
    __syncthreads();

    // Score this block's items. Pack (score_bits, ~idx) so u64 max order ==
    // (higher score, then lower index). Scores are >= 0 (emb in [0,1), counts >= 0),
    // so float bits compare monotonically as unsigned.
    int item = blockIdx.x * IPB + t;
    unsigned long long my = 0ull;
    if (t < IPB && item < NITEMS) {
        const float4* row = (const float4*)(emb + (size_t)item * EDIM);
        float sc = 0.f;
        #pragma unroll
        for (int q = 0; q < EDIM / 4; ++q) {
            float4 v = row[q];
            sc += um[q * 4 + 0] * v.x + um[q * 4 + 1] * v.y
                + um[q * 4 + 2] * v.z + um[q * 4 + 3] * v.w;
        }
        unsigned int sb = __float_as_uint(sc);
        my = ((unsigned long long)sb << 32)
           | (unsigned long long)(0xFFFFFFFFu - (unsigned int)item);
    }

    // Block-local top-K via K rounds of LDS max-tree
    for (int it = 0; it < K; ++it) {
        red[t] = my;
        __syncthreads();
        for (int st = TB2 / 2; st > 0; st >>= 1) {
            if (t < st) red[t] = umax64(red[t], red[t + st]);
            __syncthreads();
        }
        unsigned long long win = red[0];
        if (t == 0) {
            __hip_atomic_store(&cand[blockIdx.x * K + it], win,
                               __ATOMIC_RELAXED, __HIP_MEMORY_SCOPE_AGENT);
        }
        if (my == win) my = 0ull;  // item indices unique -> exactly one owner
        __syncthreads();
    }

    // Last block reduces all NB2*K candidates
    if (t == 0) {
        unsigned int prev = __hip_atomic_fetch_add(counter, 1u,
                               __ATOMIC_ACQ_REL, __HIP_MEMORY_SCOPE_AGENT);
        lastFlag = (prev == (unsigned int)(gridDim.x - 1));
    }
    __syncthreads();
    if (!lastFlag) return;

    int NC = gridDim.x * K;  // 400 <= 2*TB2
    unsigned long long a = 0ull, b = 0ull;
    if (t < NC)
        a = __hip_atomic_load(&cand[t], __ATOMIC_RELAXED, __HIP_MEMORY_SCOPE_AGENT);
    if (t + TB2 < NC)
        b = __hip_atomic_load(&cand[t + TB2], __ATOMIC_RELAXED, __HIP_MEMORY_SCOPE_AGENT);

    for (int it = 0; it < K; ++it) {
        red[t] = umax64(a, b);
        __syncthreads();
        for (int st = TB2 / 2; st > 0; st >>= 1) {
            if (t < st) red[t] = umax64(red[t], red[t + st]);
            __syncthreads();
        }
        unsigned long long win = red[0];
        if (t == 0) out[it] = (int)(0xFFFFFFFFu - (unsigned int)(win & 0xFFFFFFFFull));
        if (a == win) a = 0ull;
        if (b == win) b = 0ull;
        __syncthreads();
    }
}

extern "C" void kernel_launch(void* const* d_in, const int* in_sizes, int n_in,
                              void* d_out, int out_size, void* d_ws, size_t ws_size,
                              hipStream_t stream) {
    const int*   hist = (const int*)d_in[0];
    const float* emb  = (const float*)d_in[1];
    int H = in_sizes[0];
    int K = out_size;  // 10

    char* ws = (char*)d_ws;
    double* partials            = (double*)ws;
    unsigned int* counter       = (unsigned int*)(ws + 32768);
    unsigned long long* cand    = (unsigned long long*)(ws + 33024);

    hipMemsetAsync(counter, 0, sizeof(unsigned int), stream);

    hipLaunchKernelGGL(k1_hist_embsum, dim3(NB1), dim3(TB1), 0, stream,
                       hist, H, emb, partials);

    double invH = 1.0 / (double)H;
    hipLaunchKernelGGL(k2_score_topk, dim3(NB2), dim3(TB2), 0, stream,
                       partials, emb, invH, cand, counter, (int*)d_out, K);
}

// Round 2
// 67.619 us; speedup vs baseline: 1.4641x; 1.4641x over previous
//
#include <hip/hip_runtime.h>
#include <stdint.h>

#define NITEMS 10000
#define EDIM 32

constexpr int NB1 = 256;   // histogram blocks: 1 per CU
constexpr int TB1 = 1024;  // 16 waves/block -> 50% occupancy
constexpr int NB2 = 40;    // scoring blocks
constexpr int TB2 = 256;
constexpr int IPB = (NITEMS + NB2 - 1) / NB2;  // 250 items per scoring block

// ws layout:
// [0, 65536)            double partials[NB1][32]
// [65536, 65540)        unsigned int counter (zeroed each launch)
// [65792, 65792+3200)   u64 candidates[NB2 * K]

__global__ __launch_bounds__(TB1) void k1_hist_embsum(
    const int* __restrict__ hist, int H,
    const float* __restrict__ emb,
    double* __restrict__ partials)
{
    __shared__ int cnt[NITEMS];
    __shared__ double sred[TB1 / 32][32];

    for (int i = threadIdx.x; i < NITEMS; i += TB1) cnt[i] = 0;
    __syncthreads();

    // Phase 1: LDS histogram over this block's slice of history (vectorized int4).
    // ~4 iterations/thread at this grid -> latency chain is short.
    int tid = blockIdx.x * TB1 + threadIdx.x;
    int nth = gridDim.x * TB1;
    const int4* h4 = (const int4*)hist;
    int H4 = H >> 2;
    for (int i = tid; i < H4; i += nth) {
        int4 v = h4[i];
        atomicAdd(&cnt[v.x], 1);
        atomicAdd(&cnt[v.y], 1);
        atomicAdd(&cnt[v.z], 1);
        atomicAdd(&cnt[v.w], 1);
    }
    for (int i = (H4 << 2) + tid; i < H; i += nth) atomicAdd(&cnt[hist[i]], 1);
    __syncthreads();

    // Phase 2: partial[d] = sum_i cnt[i] * emb[i][d], accumulated in double.
    // 32 lanes of a group read one emb row (coalesced 128B), cnt broadcast.
    int d = threadIdx.x & 31;
    int g = threadIdx.x >> 5;
    constexpr int NG = TB1 / 32;  // 32 groups
    double acc = 0.0;
    for (int i = g; i < NITEMS; i += NG) {
        acc += (double)cnt[i] * (double)emb[i * EDIM + d];
    }
    sred[g][d] = acc;
    __syncthreads();
    if (threadIdx.x < 32) {
        double s = 0.0;
        #pragma unroll
        for (int g2 = 0; g2 < NG; ++g2) s += sred[g2][threadIdx.x];
        partials[blockIdx.x * 32 + threadIdx.x] = s;  // plain store, no atomics
    }
}

__device__ __forceinline__ unsigned long long umax64(unsigned long long a, unsigned long long b) {
    return a > b ? a : b;
}

// Wave-level max over 64 lanes (u64 shfl = two 32-bit shuffles under the hood)
__device__ __forceinline__ unsigned long long wave_max64(unsigned long long v) {
    #pragma unroll
    for (int off = 32; off > 0; off >>= 1)
        v = umax64(v, __shfl_xor(v, off));
    return v;
}

__global__ __launch_bounds__(TB2) void k2_score_topk(
    const double* __restrict__ partials,
    const float* __restrict__ emb,
    double invH,
    unsigned long long* __restrict__ cand,
    unsigned int* __restrict__ counter,
    int* __restrict__ out, int K)
{
    __shared__ float um[EDIM];
    __shared__ unsigned long long wred[TB2 / 64];
    __shared__ unsigned long long winner;
    __shared__ int lastFlag;

    int t = threadIdx.x;
    int lane = t & 63;
    int wv = t >> 6;
    constexpr int NW = TB2 / 64;  // 4 waves

    // Finalize user mean embedding (redundantly per block; 8KB of L2 reads)
    if (t < EDIM) {
        double s = 0.0;
        #pragma unroll 8
        for (int b = 0; b < NB1; ++b) s += partials[b * EDIM + t];
        um[t] = (float)(s * invH);
    }
    __syncthreads();

    // Score this block's items. Pack (score_bits, ~idx): u64 max order ==
    // (higher score, then lower index). Scores >= 0 (emb in [0,1), counts >= 0),
    // so float bits compare monotonically as unsigned.
    int item = blockIdx.x * IPB + t;
    unsigned long long my = 0ull;
    if (t < IPB && item < NITEMS) {
        const float4* row = (const float4*)(emb + (size_t)item * EDIM);
        float sc = 0.f;
        #pragma unroll
        for (int q = 0; q < EDIM / 4; ++q) {
            float4 v = row[q];
            sc += um[q * 4 + 0] * v.x + um[q * 4 + 1] * v.y
                + um[q * 4 + 2] * v.z + um[q * 4 + 3] * v.w;
        }
        unsigned int sb = __float_as_uint(sc);
        my = ((unsigned long long)sb << 32)
           | (unsigned long long)(0xFFFFFFFFu - (unsigned int)item);
    }

    // Block-local top-K: shfl wave-reduce + tiny LDS cross-wave reduce per round
    for (int it = 0; it < K; ++it) {
        unsigned long long w = wave_max64(my);
        if (lane == 0) wred[wv] = w;
        __syncthreads();
        if (t == 0) {
            unsigned long long win = wred[0];
            #pragma unroll
            for (int j = 1; j < NW; ++j) win = umax64(win, wred[j]);
            winner = win;
            __hip_atomic_store(&cand[blockIdx.x * K + it], win,
                               __ATOMIC_RELAXED, __HIP_MEMORY_SCOPE_AGENT);
        }
        __syncthreads();
        if (my == winner) my = 0ull;  // item indices unique -> exactly one owner
    }

    // Last block reduces all NB2*K candidates
    if (t == 0) {
        unsigned int prev = __hip_atomic_fetch_add(counter, 1u,
                               __ATOMIC_ACQ_REL, __HIP_MEMORY_SCOPE_AGENT);
        lastFlag = (prev == (unsigned int)(gridDim.x - 1));
    }
    __syncthreads();
    if (!lastFlag) return;

    int NC = gridDim.x * K;  // 400 <= 2*TB2
    unsigned long long a = 0ull, b = 0ull;
    if (t < NC)
        a = __hip_atomic_load(&cand[t], __ATOMIC_RELAXED, __HIP_MEMORY_SCOPE_AGENT);
    if (t + TB2 < NC)
        b = __hip_atomic_load(&cand[t + TB2], __ATOMIC_RELAXED, __HIP_MEMORY_SCOPE_AGENT);

    for (int it = 0; it < K; ++it) {
        unsigned long long m = umax64(a, b);
        unsigned long long w = wave_max64(m);
        if (lane == 0) wred[wv] = w;
        __syncthreads();
        if (t == 0) {
            unsigned long long win = wred[0];
            #pragma unroll
            for (int j = 1; j < NW; ++j) win = umax64(win, wred[j]);
            winner = win;
            out[it] = (int)(0xFFFFFFFFu - (unsigned int)(win & 0xFFFFFFFFull));
        }
        __syncthreads();
        unsigned long long win = winner;
        if (a == win) a = 0ull;
        if (b == win) b = 0ull;
    }
}

extern "C" void kernel_launch(void* const* d_in, const int* in_sizes, int n_in,
                              void* d_out, int out_size, void* d_ws, size_t ws_size,
                              hipStream_t stream) {
    const int*   hist = (const int*)d_in[0];
    const float* emb  = (const float*)d_in[1];
    int H = in_sizes[0];
    int K = out_size;  // 10

    char* ws = (char*)d_ws;
    double* partials            = (double*)ws;
    unsigned int* counter       = (unsigned int*)(ws + 65536);
    unsigned long long* cand    = (unsigned long long*)(ws + 65792);

    hipMemsetAsync(counter, 0, sizeof(unsigned int), stream);

    hipLaunchKernelGGL(k1_hist_embsum, dim3(NB1), dim3(TB1), 0, stream,
                       hist, H, emb, partials);

    double invH = 1.0 / (double)H;
    hipLaunchKernelGGL(k2_score_topk, dim3(NB2), dim3(TB2), 0, stream,
                       partials, emb, invH, cand, counter, (int*)d_out, K);
}

// Round 3
// 62.844 us; speedup vs baseline: 1.5753x; 1.0760x over previous
//
#include <hip/hip_runtime.h>
#include <stdint.h>

#define NITEMS 10000
#define EDIM 32
#define NWORDS 5000   // NITEMS/2 packed u16 pairs

// ---- fast path config ----
constexpr int NBH = 256;   // histogram blocks (1 per CU)
constexpr int TBH = 512;   // 4M/256 = 15625 updates/block < 65536 -> u16 safe
constexpr int NBM = 40;    // merge+embsum blocks (128 words = 256 bins each)
constexpr int TBM = 128;
constexpr int NBS = 40;    // scoring blocks
constexpr int TBS = 256;
constexpr int IPB = (NITEMS + NBS - 1) / NBS;  // 250 items per scoring block

// fast ws layout:
// [0, 5120000)              u32 hist_g[256][5000]
// [5120000, 5130240)        double partials[40][32]
// [5130240, 5130244)        u32 counter
// [5130496, 5133696)        u64 cand[40*10]
// fallback ws layout (R2, needs ~69KB):
// [0, 65536) partials[256][32]; [65536) counter; [65792) cand

// ================= fast path =================

__global__ __launch_bounds__(TBH) void k1_hist(
    const int* __restrict__ hist, int H,
    uint32_t* __restrict__ hist_g)
{
    __shared__ uint32_t cnt[NWORDS];  // two u16 bins per word
    for (int i = threadIdx.x; i < NWORDS; i += TBH) cnt[i] = 0;
    __syncthreads();

    int tid = blockIdx.x * TBH + threadIdx.x;
    int nth = gridDim.x * TBH;
    const int4* h4 = (const int4*)hist;
    int H4 = H >> 2;
    for (int i = tid; i < H4; i += nth) {
        int4 v = h4[i];
        atomicAdd(&cnt[v.x >> 1], 1u << ((v.x & 1) << 4));
        atomicAdd(&cnt[v.y >> 1], 1u << ((v.y & 1) << 4));
        atomicAdd(&cnt[v.z >> 1], 1u << ((v.z & 1) << 4));
        atomicAdd(&cnt[v.w >> 1], 1u << ((v.w & 1) << 4));
    }
    for (int i = (H4 << 2) + tid; i < H; i += nth) {
        int v = hist[i];
        atomicAdd(&cnt[v >> 1], 1u << ((v & 1) << 4));
    }
    __syncthreads();

    uint32_t* dst = hist_g + (size_t)blockIdx.x * NWORDS;
    for (int i = threadIdx.x; i < NWORDS; i += TBH) dst[i] = cnt[i];
}

__global__ __launch_bounds__(TBM) void k2_merge_embsum(
    const uint32_t* __restrict__ hist_g,
    const float* __restrict__ emb,
    double* __restrict__ partials)   // [NBM][32]
{
    __shared__ int cnt[2 * TBM];              // 256 merged bin counts
    __shared__ double sred[TBM / 32][32];

    int t = threadIdx.x;
    int w = blockIdx.x * TBM + t;             // packed-word index
    uint32_t lo = 0, hi = 0;
    if (w < NWORDS) {
        #pragma unroll 4
        for (int b = 0; b < NBH; ++b) {       // coalesced column sum
            uint32_t v = hist_g[(size_t)b * NWORDS + w];
            lo += v & 0xFFFFu;
            hi += v >> 16;
        }
    }
    cnt[2 * t]     = (int)lo;
    cnt[2 * t + 1] = (int)hi;
    __syncthreads();

    // weighted embsum for this block's 256 items (each emb row read ONCE)
    int d = t & 31;
    int g = t >> 5;                           // 4 groups of 32 lanes
    int base = blockIdx.x * (2 * TBM);
    double acc = 0.0;
    for (int i = g; i < 2 * TBM; i += TBM / 32) {
        int item = base + i;
        if (item < NITEMS)
            acc += (double)cnt[i] * (double)emb[item * EDIM + d];
    }
    sred[g][d] = acc;
    __syncthreads();
    if (t < 32) {
        double s = sred[0][t];
        #pragma unroll
        for (int g2 = 1; g2 < TBM / 32; ++g2) s += sred[g2][t];
        partials[blockIdx.x * 32 + t] = s;
    }
}

// ================= fallback (proven R2 path) =================

__global__ __launch_bounds__(1024) void k1_fb_hist_embsum(
    const int* __restrict__ hist, int H,
    const float* __restrict__ emb,
    double* __restrict__ partials)
{
    __shared__ int cnt[NITEMS];
    __shared__ double sred[32][32];

    for (int i = threadIdx.x; i < NITEMS; i += 1024) cnt[i] = 0;
    __syncthreads();

    int tid = blockIdx.x * 1024 + threadIdx.x;
    int nth = gridDim.x * 1024;
    const int4* h4 = (const int4*)hist;
    int H4 = H >> 2;
    for (int i = tid; i < H4; i += nth) {
        int4 v = h4[i];
        atomicAdd(&cnt[v.x], 1);
        atomicAdd(&cnt[v.y], 1);
        atomicAdd(&cnt[v.z], 1);
        atomicAdd(&cnt[v.w], 1);
    }
    for (int i = (H4 << 2) + tid; i < H; i += nth) atomicAdd(&cnt[hist[i]], 1);
    __syncthreads();

    int d = threadIdx.x & 31;
    int g = threadIdx.x >> 5;
    double acc = 0.0;
    for (int i = g; i < NITEMS; i += 32)
        acc += (double)cnt[i] * (double)emb[i * EDIM + d];
    sred[g][d] = acc;
    __syncthreads();
    if (threadIdx.x < 32) {
        double s = 0.0;
        #pragma unroll
        for (int g2 = 0; g2 < 32; ++g2) s += sred[g2][threadIdx.x];
        partials[blockIdx.x * 32 + threadIdx.x] = s;
    }
}

// ================= scoring + top-k (shared) =================

__device__ __forceinline__ unsigned long long umax64(unsigned long long a, unsigned long long b) {
    return a > b ? a : b;
}

__device__ __forceinline__ unsigned long long wave_max64(unsigned long long v) {
    #pragma unroll
    for (int off = 32; off > 0; off >>= 1)
        v = umax64(v, __shfl_xor(v, off));
    return v;
}

__global__ __launch_bounds__(TBS) void k3_score_topk(
    const double* __restrict__ partials, int nparts,
    const float* __restrict__ emb,
    double invH,
    unsigned long long* __restrict__ cand,
    unsigned int* __restrict__ counter,
    int* __restrict__ out, int K)
{
    __shared__ float um[EDIM];
    __shared__ unsigned long long wred[TBS / 64];
    __shared__ unsigned long long winner;
    __shared__ int lastFlag;

    int t = threadIdx.x;
    int lane = t & 63;
    int wv = t >> 6;
    constexpr int NW = TBS / 64;

    if (t < EDIM) {
        double s = 0.0;
        for (int b = 0; b < nparts; ++b) s += partials[b * EDIM + t];
        um[t] = (float)(s * invH);
    }
    __syncthreads();

    // Pack (score_bits, ~idx): u64 max == (higher score, then lower index).
    // Scores >= 0 (emb in [0,1), counts >= 0) so float bits are monotone.
    int item = blockIdx.x * IPB + t;
    unsigned long long my = 0ull;
    if (t < IPB && item < NITEMS) {
        const float4* row = (const float4*)(emb + (size_t)item * EDIM);
        float sc = 0.f;
        #pragma unroll
        for (int q = 0; q < EDIM / 4; ++q) {
            float4 v = row[q];
            sc += um[q * 4 + 0] * v.x + um[q * 4 + 1] * v.y
                + um[q * 4 + 2] * v.z + um[q * 4 + 3] * v.w;
        }
        unsigned int sb = __float_as_uint(sc);
        my = ((unsigned long long)sb << 32)
           | (unsigned long long)(0xFFFFFFFFu - (unsigned int)item);
    }

    for (int it = 0; it < K; ++it) {
        unsigned long long w = wave_max64(my);
        if (lane == 0) wred[wv] = w;
        __syncthreads();
        if (t == 0) {
            unsigned long long win = wred[0];
            #pragma unroll
            for (int j = 1; j < NW; ++j) win = umax64(win, wred[j]);
            winner = win;
            __hip_atomic_store(&cand[blockIdx.x * K + it], win,
                               __ATOMIC_RELAXED, __HIP_MEMORY_SCOPE_AGENT);
        }
        __syncthreads();
        if (my == winner) my = 0ull;
    }

    if (t == 0) {
        unsigned int prev = __hip_atomic_fetch_add(counter, 1u,
                               __ATOMIC_ACQ_REL, __HIP_MEMORY_SCOPE_AGENT);
        lastFlag = (prev == (unsigned int)(gridDim.x - 1));
    }
    __syncthreads();
    if (!lastFlag) return;

    int NC = gridDim.x * K;
    unsigned long long a = 0ull, b = 0ull;
    if (t < NC)
        a = __hip_atomic_load(&cand[t], __ATOMIC_RELAXED, __HIP_MEMORY_SCOPE_AGENT);
    if (t + TBS < NC)
        b = __hip_atomic_load(&cand[t + TBS], __ATOMIC_RELAXED, __HIP_MEMORY_SCOPE_AGENT);

    for (int it = 0; it < K; ++it) {
        unsigned long long m = umax64(a, b);
        unsigned long long w = wave_max64(m);
        if (lane == 0) wred[wv] = w;
        __syncthreads();
        if (t == 0) {
            unsigned long long win = wred[0];
            #pragma unroll
            for (int j = 1; j < NW; ++j) win = umax64(win, wred[j]);
            winner = win;
            out[it] = (int)(0xFFFFFFFFu - (unsigned int)(win & 0xFFFFFFFFull));
        }
        __syncthreads();
        unsigned long long win = winner;
        if (a == win) a = 0ull;
        if (b == win) b = 0ull;
    }
}

extern "C" void kernel_launch(void* const* d_in, const int* in_sizes, int n_in,
                              void* d_out, int out_size, void* d_ws, size_t ws_size,
                              hipStream_t stream) {
    const int*   hist = (const int*)d_in[0];
    const float* emb  = (const float*)d_in[1];
    int H = in_sizes[0];
    int K = out_size;  // 10
    double invH = 1.0 / (double)H;
    char* ws = (char*)d_ws;

    constexpr size_t FAST_WS = 5133696;

    if (ws_size >= FAST_WS) {
        uint32_t* hist_g         = (uint32_t*)ws;
        double* partials         = (double*)(ws + 5120000);
        unsigned int* counter    = (unsigned int*)(ws + 5130240);
        unsigned long long* cand = (unsigned long long*)(ws + 5130496);

        hipMemsetAsync(counter, 0, sizeof(unsigned int), stream);
        hipLaunchKernelGGL(k1_hist, dim3(NBH), dim3(TBH), 0, stream,
                           hist, H, hist_g);
        hipLaunchKernelGGL(k2_merge_embsum, dim3(NBM), dim3(TBM), 0, stream,
                           hist_g, emb, partials);
        hipLaunchKernelGGL(k3_score_topk, dim3(NBS), dim3(TBS), 0, stream,
                           partials, NBM, emb, invH, cand, counter, (int*)d_out, K);
    } else {
        double* partials         = (double*)ws;
        unsigned int* counter    = (unsigned int*)(ws + 65536);
        unsigned long long* cand = (unsigned long long*)(ws + 65792);

        hipMemsetAsync(counter, 0, sizeof(unsigned int), stream);
        hipLaunchKernelGGL(k1_fb_hist_embsum, dim3(256), dim3(1024), 0, stream,
                           hist, H, emb, partials);
        hipLaunchKernelGGL(k3_score_topk, dim3(NBS), dim3(TBS), 0, stream,
                           partials, 256, emb, invH, cand, counter, (int*)d_out, K);
    }
}

// Round 4
// 34.863 us; speedup vs baseline: 2.8397x; 1.8026x over previous
//
#include <hip/hip_runtime.h>
#include <stdint.h>

#define NITEMS 10000
#define EDIM 32
#define NWORDS 5000   // NITEMS/2 packed u16 pairs

// ---- fast path config ----
constexpr int NBH = 255;   // histogram blocks (fits ws; per-block updates < 2^16)
constexpr int TBH = 1024;  // 16 waves/block -> 4 waves/SIMD
constexpr int NBE = 80;    // embsum blocks
constexpr int TBE = 256;
constexpr int IPE = NITEMS / NBE;              // 125 items per embsum block
constexpr int NBS = 40;    // scoring blocks
constexpr int TBS = 256;
constexpr int IPB = (NITEMS + NBS - 1) / NBS;  // 250 items per scoring block

// fast ws layout (needs 5,120,004 B; proven ws_size >= 5,133,696):
//   [0, 5,100,000)            u32 hist_g[255][5000]     (live: k1 -> k2a)
//   [5,100,000, 5,120,000)    u32 hist_sum[5000]        (zeroed by k1; k2a atomics; k2b reads)
//   [5,120,000, 5,120,004)    u32 counter               (zeroed by k1; k3)
//   aliases into dead hist_g region (born after k2a finishes reading hist_g):
//   [0, 20,480)               double partials[80][32]   (k2b writes, k3 reads)
//   [20,480, 23,680)          u64 cand[40*10]           (k3 only)
// fallback ws layout (R2 path, ~69KB)

// ================= fast path =================

__global__ __launch_bounds__(TBH) void k1_hist(
    const int* __restrict__ hist, int H,
    uint32_t* __restrict__ hist_g,
    uint32_t* __restrict__ hist_sum,
    unsigned int* __restrict__ counter)
{
    __shared__ uint32_t cnt[NWORDS];  // two u16 bins per word
    for (int i = threadIdx.x; i < NWORDS; i += TBH) cnt[i] = 0;

    // block 0 also zeroes the global accumulators consumed by k2a/k3
    if (blockIdx.x == 0) {
        for (int i = threadIdx.x; i < NWORDS; i += TBH) hist_sum[i] = 0;
        if (threadIdx.x == 0) *counter = 0;
    }
    __syncthreads();

    int tid = blockIdx.x * TBH + threadIdx.x;
    int nth = gridDim.x * TBH;
    const int4* h4 = (const int4*)hist;
    int H4 = H >> 2;
    for (int i = tid; i < H4; i += nth) {
        int4 v = h4[i];
        atomicAdd(&cnt[v.x >> 1], 1u << ((v.x & 1) << 4));
        atomicAdd(&cnt[v.y >> 1], 1u << ((v.y & 1) << 4));
        atomicAdd(&cnt[v.z >> 1], 1u << ((v.z & 1) << 4));
        atomicAdd(&cnt[v.w >> 1], 1u << ((v.w & 1) << 4));
    }
    for (int i = (H4 << 2) + tid; i < H; i += nth) {
        int v = hist[i];
        atomicAdd(&cnt[v >> 1], 1u << ((v & 1) << 4));
    }
    __syncthreads();

    uint32_t* dst = hist_g + (size_t)blockIdx.x * NWORDS;
    for (int i = threadIdx.x; i < NWORDS; i += TBH) dst[i] = cnt[i];
}

// 2D merge: grid (40, 8), block 128. Thread sums 32 rows of one packed word,
// then one device atomicAdd. Packed-u16 carry-safe: final per-bin totals ~600.
__global__ __launch_bounds__(128) void k2a_merge(
    const uint32_t* __restrict__ hist_g,
    uint32_t* __restrict__ hist_sum)
{
    int w = blockIdx.x * 128 + threadIdx.x;
    if (w >= NWORDS) return;
    int r0 = blockIdx.y * 32;
    int r1 = r0 + 32; if (r1 > NBH) r1 = NBH;
    uint32_t lo = 0, hi = 0;
    #pragma unroll 8
    for (int r = r0; r < r1; ++r) {
        uint32_t v = hist_g[(size_t)r * NWORDS + w];
        lo += v & 0xFFFFu;
        hi += v >> 16;
    }
    atomicAdd(&hist_sum[w], (hi << 16) | lo);
}

__global__ __launch_bounds__(TBE) void k2b_embsum(
    const uint32_t* __restrict__ hist_sum,
    const float* __restrict__ emb,
    double* __restrict__ partials)   // [NBE][32]
{
    __shared__ double sred[TBE / 32][32];
    int t = threadIdx.x;
    int d = t & 31;
    int g = t >> 5;                   // 8 groups of 32 lanes
    int base = blockIdx.x * IPE;

    double acc = 0.0;
    for (int i = g; i < IPE; i += TBE / 32) {
        int item = base + i;
        uint32_t wv = hist_sum[item >> 1];
        int c = (item & 1) ? (int)(wv >> 16) : (int)(wv & 0xFFFFu);
        acc += (double)c * (double)emb[item * EDIM + d];
    }
    sred[g][d] = acc;
    __syncthreads();
    if (t < 32) {
        double s = sred[0][t];
        #pragma unroll
        for (int g2 = 1; g2 < TBE / 32; ++g2) s += sred[g2][t];
        partials[blockIdx.x * 32 + t] = s;
    }
}

// ================= fallback (proven R2 path) =================

__global__ __launch_bounds__(1024) void k1_fb_hist_embsum(
    const int* __restrict__ hist, int H,
    const float* __restrict__ emb,
    double* __restrict__ partials)
{
    __shared__ int cnt[NITEMS];
    __shared__ double sred[32][32];

    for (int i = threadIdx.x; i < NITEMS; i += 1024) cnt[i] = 0;
    __syncthreads();

    int tid = blockIdx.x * 1024 + threadIdx.x;
    int nth = gridDim.x * 1024;
    const int4* h4 = (const int4*)hist;
    int H4 = H >> 2;
    for (int i = tid; i < H4; i += nth) {
        int4 v = h4[i];
        atomicAdd(&cnt[v.x], 1);
        atomicAdd(&cnt[v.y], 1);
        atomicAdd(&cnt[v.z], 1);
        atomicAdd(&cnt[v.w], 1);
    }
    for (int i = (H4 << 2) + tid; i < H; i += nth) atomicAdd(&cnt[hist[i]], 1);
    __syncthreads();

    int d = threadIdx.x & 31;
    int g = threadIdx.x >> 5;
    double acc = 0.0;
    for (int i = g; i < NITEMS; i += 32)
        acc += (double)cnt[i] * (double)emb[i * EDIM + d];
    sred[g][d] = acc;
    __syncthreads();
    if (threadIdx.x < 32) {
        double s = 0.0;
        #pragma unroll
        for (int g2 = 0; g2 < 32; ++g2) s += sred[g2][threadIdx.x];
        partials[blockIdx.x * 32 + threadIdx.x] = s;
    }
}

// ================= scoring + top-k (shared) =================

__device__ __forceinline__ unsigned long long umax64(unsigned long long a, unsigned long long b) {
    return a > b ? a : b;
}

__device__ __forceinline__ unsigned long long wave_max64(unsigned long long v) {
    #pragma unroll
    for (int off = 32; off > 0; off >>= 1)
        v = umax64(v, __shfl_xor(v, off));
    return v;
}

__global__ __launch_bounds__(TBS) void k3_score_topk(
    const double* __restrict__ partials, int nparts,
    const float* __restrict__ emb,
    double invH,
    unsigned long long* __restrict__ cand,
    unsigned int* __restrict__ counter,
    int* __restrict__ out, int K)
{
    __shared__ double sred[TBS / 32][32];
    __shared__ float um[EDIM];
    __shared__ unsigned long long wred[TBS / 64];
    __shared__ unsigned long long winner;
    __shared__ int lastFlag;

    int t = threadIdx.x;
    int lane = t & 63;
    int wv = t >> 6;
    constexpr int NW = TBS / 64;

    // um: group-parallel partial sum (8 groups x 32 dims), short latency chains
    {
        int d = t & 31;
        int g = t >> 5;
        double acc = 0.0;
        for (int b = g; b < nparts; b += TBS / 32)
            acc += partials[b * EDIM + d];
        sred[g][d] = acc;
        __syncthreads();
        if (t < 32) {
            double s = sred[0][t];
            #pragma unroll
            for (int g2 = 1; g2 < TBS / 32; ++g2) s += sred[g2][t];
            um[t] = (float)(s * invH);
        }
        __syncthreads();
    }

    // Pack (score_bits, ~idx): u64 max == (higher score, then lower index).
    // Scores >= 0 (emb in [0,1), counts >= 0) so float bits are monotone.
    int item = blockIdx.x * IPB + t;
    unsigned long long my = 0ull;
    if (t < IPB && item < NITEMS) {
        const float4* row = (const float4*)(emb + (size_t)item * EDIM);
        float sc = 0.f;
        #pragma unroll
        for (int q = 0; q < EDIM / 4; ++q) {
            float4 v = row[q];
            sc += um[q * 4 + 0] * v.x + um[q * 4 + 1] * v.y
                + um[q * 4 + 2] * v.z + um[q * 4 + 3] * v.w;
        }
        unsigned int sb = __float_as_uint(sc);
        my = ((unsigned long long)sb << 32)
           | (unsigned long long)(0xFFFFFFFFu - (unsigned int)item);
    }

    for (int it = 0; it < K; ++it) {
        unsigned long long w = wave_max64(my);
        if (lane == 0) wred[wv] = w;
        __syncthreads();
        if (t == 0) {
            unsigned long long win = wred[0];
            #pragma unroll
            for (int j = 1; j < NW; ++j) win = umax64(win, wred[j]);
            winner = win;
            __hip_atomic_store(&cand[blockIdx.x * K + it], win,
                               __ATOMIC_RELAXED, __HIP_MEMORY_SCOPE_AGENT);
        }
        __syncthreads();
        if (my == winner) my = 0ull;
    }

    if (t == 0) {
        unsigned int prev = __hip_atomic_fetch_add(counter, 1u,
                               __ATOMIC_ACQ_REL, __HIP_MEMORY_SCOPE_AGENT);
        lastFlag = (prev == (unsigned int)(gridDim.x - 1));
    }
    __syncthreads();
    if (!lastFlag) return;

    int NC = gridDim.x * K;
    unsigned long long a = 0ull, b = 0ull;
    if (t < NC)
        a = __hip_atomic_load(&cand[t], __ATOMIC_RELAXED, __HIP_MEMORY_SCOPE_AGENT);
    if (t + TBS < NC)
        b = __hip_atomic_load(&cand[t + TBS], __ATOMIC_RELAXED, __HIP_MEMORY_SCOPE_AGENT);

    for (int it = 0; it < K; ++it) {
        unsigned long long m = umax64(a, b);
        unsigned long long w = wave_max64(m);
        if (lane == 0) wred[wv] = w;
        __syncthreads();
        if (t == 0) {
            unsigned long long win = wred[0];
            #pragma unroll
            for (int j = 1; j < NW; ++j) win = umax64(win, wred[j]);
            winner = win;
            out[it] = (int)(0xFFFFFFFFu - (unsigned int)(win & 0xFFFFFFFFull));
        }
        __syncthreads();
        unsigned long long win = winner;
        if (a == win) a = 0ull;
        if (b == win) b = 0ull;
    }
}

extern "C" void kernel_launch(void* const* d_in, const int* in_sizes, int n_in,
                              void* d_out, int out_size, void* d_ws, size_t ws_size,
                              hipStream_t stream) {
    const int*   hist = (const int*)d_in[0];
    const float* emb  = (const float*)d_in[1];
    int H = in_sizes[0];
    int K = out_size;  // 10
    double invH = 1.0 / (double)H;
    char* ws = (char*)d_ws;

    constexpr size_t FAST_WS = 5120004;

    if (ws_size >= FAST_WS) {
        uint32_t* hist_g         = (uint32_t*)ws;
        uint32_t* hist_sum       = (uint32_t*)(ws + 5100000);
        unsigned int* counter    = (unsigned int*)(ws + 5120000);
        double* partials         = (double*)ws;                         // aliases dead hist_g
        unsigned long long* cand = (unsigned long long*)(ws + 20480);   // aliases dead hist_g

        hipLaunchKernelGGL(k1_hist, dim3(NBH), dim3(TBH), 0, stream,
                           hist, H, hist_g, hist_sum, counter);
        hipLaunchKernelGGL(k2a_merge, dim3((NWORDS + 127) / 128, 8), dim3(128), 0, stream,
                           hist_g, hist_sum);
        hipLaunchKernelGGL(k2b_embsum, dim3(NBE), dim3(TBE), 0, stream,
                           hist_sum, emb, partials);
        hipLaunchKernelGGL(k3_score_topk, dim3(NBS), dim3(TBS), 0, stream,
                           partials, NBE, emb, invH, cand, counter, (int*)d_out, K);
    } else {
        double* partials         = (double*)ws;
        unsigned int* counter    = (unsigned int*)(ws + 65536);
        unsigned long long* cand = (unsigned long long*)(ws + 65792);

        hipMemsetAsync(counter, 0, sizeof(unsigned int), stream);
        hipLaunchKernelGGL(k1_fb_hist_embsum, dim3(256), dim3(1024), 0, stream,
                           hist, H, emb, partials);
        hipLaunchKernelGGL(k3_score_topk, dim3(NBS), dim3(TBS), 0, stream,
                           partials, 256, emb, invH, cand, counter, (int*)d_out, K);
    }
}

// Round 5
// 29.159 us; speedup vs baseline: 3.3951x; 1.1956x over previous
//
#include <hip/hip_runtime.h>
#include <stdint.h>

#define NITEMS 10000
#define EDIM 32
#define NWORDS 5000   // NITEMS/2 packed u16 pairs

// ---- fast path config ----
constexpr int NBH = 256;   // histogram blocks (2/CU, 32 waves/CU)
constexpr int TBH = 1024;  // per-block updates = 4M/256 = 15625 < 2^16 -> u16 safe
constexpr int NBE = 40;    // merge+embsum blocks
constexpr int TBE = 1024;
constexpr int WPB = NWORDS / NBE;   // 125 packed words per block
constexpr int IPEB = 2 * WPB;       // 250 items per block
constexpr int CHUNKS = 8;           // row chunks in merge phase
constexpr int RPC = NBH / CHUNKS;   // 32 rows per chunk
constexpr int NBS = 40;    // scoring blocks
constexpr int TBS = 256;
constexpr int IPB = (NITEMS + NBS - 1) / NBS;  // 250 items per scoring block

// fast ws layout (needs 5,133,696 B; ws is ~268 MB):
//   [0, 5,120,000)            u32 hist_g[256][5000]
//   [5,120,000, 5,130,240)    double partials[40][32]
//   [5,130,240, 5,130,244)    u32 counter   (zeroed by k1 blk0; k3 uses)
//   [5,130,496, 5,133,696)    u64 cand[40*10]

// ================= fast path =================

__global__ __launch_bounds__(TBH) void k1_hist(
    const int* __restrict__ hist, int H,
    uint32_t* __restrict__ hist_g,
    unsigned int* __restrict__ counter)
{
    __shared__ uint32_t cnt[NWORDS];  // two u16 bins per word
    for (int i = threadIdx.x; i < NWORDS; i += TBH) cnt[i] = 0;
    if (blockIdx.x == 0 && threadIdx.x == 0) *counter = 0;  // consumed by k3 (stream-ordered)
    __syncthreads();

    int tid = blockIdx.x * TBH + threadIdx.x;
    int nth = gridDim.x * TBH;
    const int4* h4 = (const int4*)hist;
    int H4 = H >> 2;
    for (int i = tid; i < H4; i += nth) {       // ~4 iterations
        int4 v = h4[i];
        atomicAdd(&cnt[v.x >> 1], 1u << ((v.x & 1) << 4));
        atomicAdd(&cnt[v.y >> 1], 1u << ((v.y & 1) << 4));
        atomicAdd(&cnt[v.z >> 1], 1u << ((v.z & 1) << 4));
        atomicAdd(&cnt[v.w >> 1], 1u << ((v.w & 1) << 4));
    }
    for (int i = (H4 << 2) + tid; i < H; i += nth) {
        int v = hist[i];
        atomicAdd(&cnt[v >> 1], 1u << ((v & 1) << 4));
    }
    __syncthreads();

    uint32_t* dst = hist_g + (size_t)blockIdx.x * NWORDS;
    for (int i = threadIdx.x; i < NWORDS; i += TBH) dst[i] = cnt[i];
}

// Merge + weighted embsum fused. Grid: 40 x 1024.
// Phase 1: thread (w_idx = t&127 [<125], chunk = t>>7) sums 32 rows of one
//          packed word (coalesced 500B rows, independent loads -> deep ILP).
// Phase 2: 32 groups x 32 dims weighted embsum over this block's 250 items.
__global__ __launch_bounds__(TBE) void k2_merge_embsum(
    const uint32_t* __restrict__ hist_g,
    const float* __restrict__ emb,
    double* __restrict__ partials)   // [NBE][32]
{
    __shared__ uint32_t partLo[CHUNKS][WPB + 3];
    __shared__ uint32_t partHi[CHUNKS][WPB + 3];
    __shared__ int cnt[IPEB];
    __shared__ double sred[TBE / 32][32];

    int t = threadIdx.x;
    int w_idx = t & 127;
    int chunk = t >> 7;          // 0..7
    int wbase = blockIdx.x * WPB;

    if (w_idx < WPB) {
        uint32_t lo = 0, hi = 0;
        const uint32_t* src = hist_g + (size_t)(chunk * RPC) * NWORDS + wbase + w_idx;
        #pragma unroll 8
        for (int r = 0; r < RPC; ++r) {
            uint32_t v = src[(size_t)r * NWORDS];
            lo += v & 0xFFFFu;
            hi += v >> 16;
        }
        partLo[chunk][w_idx] = lo;
        partHi[chunk][w_idx] = hi;
    }
    __syncthreads();

    if (t < WPB) {
        uint32_t lo = 0, hi = 0;
        #pragma unroll
        for (int c = 0; c < CHUNKS; ++c) {
            lo += partLo[c][t];
            hi += partHi[c][t];
        }
        cnt[2 * t]     = (int)lo;
        cnt[2 * t + 1] = (int)hi;
    }
    __syncthreads();

    // Phase 2: weighted embsum; each emb row read once chip-wide.
    int d = t & 31;
    int g = t >> 5;              // 32 groups
    int ibase = blockIdx.x * IPEB;
    double acc = 0.0;
    for (int i = g; i < IPEB; i += TBE / 32) {   // ~8 iterations
        acc += (double)cnt[i] * (double)emb[(ibase + i) * EDIM + d];
    }
    sred[g][d] = acc;
    __syncthreads();
    if (t < 32) {
        double s = sred[0][t];
        #pragma unroll
        for (int g2 = 1; g2 < TBE / 32; ++g2) s += sred[g2][t];
        partials[blockIdx.x * 32 + t] = s;
    }
}

// ================= fallback (proven R2 path) =================

__global__ __launch_bounds__(1024) void k1_fb_hist_embsum(
    const int* __restrict__ hist, int H,
    const float* __restrict__ emb,
    double* __restrict__ partials)
{
    __shared__ int cnt[NITEMS];
    __shared__ double sred[32][32];

    for (int i = threadIdx.x; i < NITEMS; i += 1024) cnt[i] = 0;
    __syncthreads();

    int tid = blockIdx.x * 1024 + threadIdx.x;
    int nth = gridDim.x * 1024;
    const int4* h4 = (const int4*)hist;
    int H4 = H >> 2;
    for (int i = tid; i < H4; i += nth) {
        int4 v = h4[i];
        atomicAdd(&cnt[v.x], 1);
        atomicAdd(&cnt[v.y], 1);
        atomicAdd(&cnt[v.z], 1);
        atomicAdd(&cnt[v.w], 1);
    }
    for (int i = (H4 << 2) + tid; i < H; i += nth) atomicAdd(&cnt[hist[i]], 1);
    __syncthreads();

    int d = threadIdx.x & 31;
    int g = threadIdx.x >> 5;
    double acc = 0.0;
    for (int i = g; i < NITEMS; i += 32)
        acc += (double)cnt[i] * (double)emb[i * EDIM + d];
    sred[g][d] = acc;
    __syncthreads();
    if (threadIdx.x < 32) {
        double s = 0.0;
        #pragma unroll
        for (int g2 = 0; g2 < 32; ++g2) s += sred[g2][threadIdx.x];
        partials[blockIdx.x * 32 + threadIdx.x] = s;
    }
}

// ================= scoring + top-k (shared) =================

__device__ __forceinline__ unsigned long long umax64(unsigned long long a, unsigned long long b) {
    return a > b ? a : b;
}

__device__ __forceinline__ unsigned long long wave_max64(unsigned long long v) {
    #pragma unroll
    for (int off = 32; off > 0; off >>= 1)
        v = umax64(v, __shfl_xor(v, off));
    return v;
}

__global__ __launch_bounds__(TBS) void k3_score_topk(
    const double* __restrict__ partials, int nparts,
    const float* __restrict__ emb,
    double invH,
    unsigned long long* __restrict__ cand,
    unsigned int* __restrict__ counter,
    int* __restrict__ out, int K)
{
    __shared__ double sred[TBS / 32][32];
    __shared__ float um[EDIM];
    __shared__ unsigned long long wred[TBS / 64];
    __shared__ unsigned long long winner;
    __shared__ int lastFlag;

    int t = threadIdx.x;
    int lane = t & 63;
    int wv = t >> 6;
    constexpr int NW = TBS / 64;

    {
        int d = t & 31;
        int g = t >> 5;
        double acc = 0.0;
        for (int b = g; b < nparts; b += TBS / 32)
            acc += partials[b * EDIM + d];
        sred[g][d] = acc;
        __syncthreads();
        if (t < 32) {
            double s = sred[0][t];
            #pragma unroll
            for (int g2 = 1; g2 < TBS / 32; ++g2) s += sred[g2][t];
            um[t] = (float)(s * invH);
        }
        __syncthreads();
    }

    // Pack (score_bits, ~idx): u64 max == (higher score, then lower index).
    // Scores >= 0 (emb in [0,1), counts >= 0) so float bits are monotone.
    int item = blockIdx.x * IPB + t;
    unsigned long long my = 0ull;
    if (t < IPB && item < NITEMS) {
        const float4* row = (const float4*)(emb + (size_t)item * EDIM);
        float sc = 0.f;
        #pragma unroll
        for (int q = 0; q < EDIM / 4; ++q) {
            float4 v = row[q];
            sc += um[q * 4 + 0] * v.x + um[q * 4 + 1] * v.y
                + um[q * 4 + 2] * v.z + um[q * 4 + 3] * v.w;
        }
        unsigned int sb = __float_as_uint(sc);
        my = ((unsigned long long)sb << 32)
           | (unsigned long long)(0xFFFFFFFFu - (unsigned int)item);
    }

    for (int it = 0; it < K; ++it) {
        unsigned long long w = wave_max64(my);
        if (lane == 0) wred[wv] = w;
        __syncthreads();
        if (t == 0) {
            unsigned long long win = wred[0];
            #pragma unroll
            for (int j = 1; j < NW; ++j) win = umax64(win, wred[j]);
            winner = win;
            __hip_atomic_store(&cand[blockIdx.x * K + it], win,
                               __ATOMIC_RELAXED, __HIP_MEMORY_SCOPE_AGENT);
        }
        __syncthreads();
        if (my == winner) my = 0ull;
    }

    if (t == 0) {
        unsigned int prev = __hip_atomic_fetch_add(counter, 1u,
                               __ATOMIC_ACQ_REL, __HIP_MEMORY_SCOPE_AGENT);
        lastFlag = (prev == (unsigned int)(gridDim.x - 1));
    }
    __syncthreads();
    if (!lastFlag) return;

    int NC = gridDim.x * K;
    unsigned long long a = 0ull, b = 0ull;
    if (t < NC)
        a = __hip_atomic_load(&cand[t], __ATOMIC_RELAXED, __HIP_MEMORY_SCOPE_AGENT);
    if (t + TBS < NC)
        b = __hip_atomic_load(&cand[t + TBS], __ATOMIC_RELAXED, __HIP_MEMORY_SCOPE_AGENT);

    for (int it = 0; it < K; ++it) {
        unsigned long long m = umax64(a, b);
        unsigned long long w = wave_max64(m);
        if (lane == 0) wred[wv] = w;
        __syncthreads();
        if (t == 0) {
            unsigned long long win = wred[0];
            #pragma unroll
            for (int j = 1; j < NW; ++j) win = umax64(win, wred[j]);
            winner = win;
            out[it] = (int)(0xFFFFFFFFu - (unsigned int)(win & 0xFFFFFFFFull));
        }
        __syncthreads();
        unsigned long long win = winner;
        if (a == win) a = 0ull;
        if (b == win) b = 0ull;
    }
}

extern "C" void kernel_launch(void* const* d_in, const int* in_sizes, int n_in,
                              void* d_out, int out_size, void* d_ws, size_t ws_size,
                              hipStream_t stream) {
    const int*   hist = (const int*)d_in[0];
    const float* emb  = (const float*)d_in[1];
    int H = in_sizes[0];
    int K = out_size;  // 10
    double invH = 1.0 / (double)H;
    char* ws = (char*)d_ws;

    constexpr size_t FAST_WS = 5133696;

    if (ws_size >= FAST_WS) {
        uint32_t* hist_g         = (uint32_t*)ws;
        double* partials         = (double*)(ws + 5120000);
        unsigned int* counter    = (unsigned int*)(ws + 5130240);
        unsigned long long* cand = (unsigned long long*)(ws + 5130496);

        hipLaunchKernelGGL(k1_hist, dim3(NBH), dim3(TBH), 0, stream,
                           hist, H, hist_g, counter);
        hipLaunchKernelGGL(k2_merge_embsum, dim3(NBE), dim3(TBE), 0, stream,
                           hist_g, emb, partials);
        hipLaunchKernelGGL(k3_score_topk, dim3(NBS), dim3(TBS), 0, stream,
                           partials, NBE, emb, invH, cand, counter, (int*)d_out, K);
    } else {
        double* partials         = (double*)ws;
        unsigned int* counter    = (unsigned int*)(ws + 65536);
        unsigned long long* cand = (unsigned long long*)(ws + 65792);

        hipMemsetAsync(counter, 0, sizeof(unsigned int), stream);
        hipLaunchKernelGGL(k1_fb_hist_embsum, dim3(256), dim3(1024), 0, stream,
                           hist, H, emb, partials);
        hipLaunchKernelGGL(k3_score_topk, dim3(NBS), dim3(TBS), 0, stream,
                           partials, 256, emb, invH, cand, counter, (int*)d_out, K);
    }
}